// Round 3
// baseline (311.683 us; speedup 1.0000x reference)
//
#include <hip/hip_runtime.h>
#include <hip/hip_bf16.h>

#define NPOS 4096          // 64*64 positions
#define CD   64            // channels
#define NB   4             // batch
#define PADW 66
#define PADN (66*66)       // padded positions (zero halo)
#define NSEG 2             // attention n-split
#define NT   (NPOS / NSEG / 64)
#define LOG2E 1.4426950408889634f

extern "C" __device__ float __ocml_exp2_f32(float);

typedef __bf16 bf16x8_t __attribute__((ext_vector_type(8)));
typedef float  f32x4_t  __attribute__((ext_vector_type(4)));

static __device__ __forceinline__ unsigned short f2bf(float f) {
    return __builtin_bit_cast(unsigned short, __float2bfloat16(f));
}

static __device__ __forceinline__ void gload_lds16(const void* g, void* l) {
    __builtin_amdgcn_global_load_lds(
        (const __attribute__((address_space(1))) void*)g,
        (__attribute__((address_space(3))) void*)l, 16, 0, 0);
}

// ---------------------------------------------------------------------------
// prep: fused {halo-zero, weight-repack, input-pack} in one launch.
// grid 672 = 16 halo + 144 wrepack + 512 pack. block 256.
//  halo: zero the 260 halo positions of each of 16 padded images (4 bufs x 4 b)
//  wrepack: OIHW fp32 -> per-lane MFMA B-frags bf16 Wf[f][cot][lane][8],
//           BN scale folded; K-convs (f in [36,54)+[72,90)) also x log2(e)
//  pack: fp32 NCHW -> bf16 zero-haloed position-major [b][66*66][64]
// ---------------------------------------------------------------------------
__global__ __launch_bounds__(256) void prep_kernel(
    const float* __restrict__ x, const float* __restrict__ y,
    const float* __restrict__ qw, const float* __restrict__ rkw,
    const float* __restrict__ rvw, const float* __restrict__ ikw,
    const float* __restrict__ ivw, const float* __restrict__ srw,
    const float* __restrict__ qs, const float* __restrict__ rks,
    const float* __restrict__ rvs, const float* __restrict__ iks,
    const float* __restrict__ ivs, const float* __restrict__ srs,
    unsigned short* __restrict__ pads, unsigned short* __restrict__ Wf)
{
    const int bx = blockIdx.x;
    if (bx < 16) {
        // ---- halo zero: image bx of the 16 contiguous padded images ----
        unsigned short* p = pads + (size_t)bx * PADN * CD;
        const uint4 z = make_uint4(0, 0, 0, 0);
        for (int idx = threadIdx.x; idx < 260 * 8; idx += 256) {
            const int pi = idx >> 3, ch = idx & 7;
            int pos;
            if (pi < 66)       pos = pi;
            else if (pi < 132) pos = 65 * PADW + (pi - 66);
            else { const int rem = pi - 132;
                   pos = (1 + (rem >> 1)) * PADW + ((rem & 1) ? 65 : 0); }
            *(uint4*)(p + (size_t)pos * CD + ch * 8) = z;
        }
        return;
    }
    if (bx < 160) {
        // ---- weight repack, f = bx-16 in [0,144) ----
        const int f = bx - 16;
        const float* w; const float* s; int cin, local;
        if (f < 36)       { w = qw;  s = qs;  cin = 128; local = f; }
        else if (f < 54)  { w = rkw; s = rks; cin = 64;  local = f - 36; }
        else if (f < 72)  { w = rvw; s = rvs; cin = 64;  local = f - 54; }
        else if (f < 90)  { w = ikw; s = iks; cin = 64;  local = f - 72; }
        else if (f < 108) { w = ivw; s = ivs; cin = 64;  local = f - 90; }
        else              { w = srw; s = srs; cin = 128; local = f - 108; }
        const int src = (cin == 128) ? local / 18 : 0;
        const int rem = (cin == 128) ? local % 18 : local;
        const int tap = rem >> 1, kt = rem & 1;
        const int t = threadIdx.x, cot = t >> 6, l = t & 63;
        const int co = cot * 16 + (l & 15);
        const float kmul = ((f >= 36 && f < 54) || (f >= 72 && f < 90)) ? LOG2E : 1.0f;
        const float sc = s[co] * kmul;
        unsigned short us[8];
#pragma unroll
        for (int e = 0; e < 8; ++e) {
            const int ci = src * 64 + kt * 32 + ((l >> 4) * 8) + e;
            us[e] = f2bf(w[((size_t)co * cin + ci) * 9 + tap] * sc);
        }
        *(uint4*)(Wf + ((size_t)(f * 4 + cot) * 64 + l) * 8) = *(uint4*)us;
        return;
    }
    // ---- pack: idx = bx-160 in [0,512): h, b, src ----
    {
        const int idx = bx - 160;
        const int h = idx & 63, b = (idx >> 6) & 3, src = idx >> 8;
        const float* in = src ? y : x;
        unsigned short* out = pads + (size_t)src * NB * PADN * CD;  // xpad or ypad
        __shared__ float t[64][65];
        const int tt = threadIdx.x;
        {
            const int ci = tt >> 2, w0 = (tt & 3) * 16;
            const float* p = in + ((size_t)b * 64 + ci) * NPOS + h * 64 + w0;
#pragma unroll
            for (int j = 0; j < 16; j += 4) {
                float4 v = *(const float4*)(p + j);
                t[ci][w0 + j] = v.x; t[ci][w0 + j + 1] = v.y;
                t[ci][w0 + j + 2] = v.z; t[ci][w0 + j + 3] = v.w;
            }
        }
        __syncthreads();
        const int w = tt >> 2, c0 = (tt & 3) * 16;
        unsigned short us[16];
#pragma unroll
        for (int j = 0; j < 16; ++j) us[j] = f2bf(t[c0 + j][w]);
        unsigned short* q = out + ((size_t)b * PADN + (h + 1) * PADW + (w + 1)) * CD + c0;
        *(uint4*)q = *(uint4*)us;
        *(uint4*)(q + 8) = *(uint4*)(us + 8);
    }
}

// ---------------------------------------------------------------------------
// Implicit-GEMM conv3x3 via MFMA, 2 batches per block (weight frags reused).
// Block = one h row (64 pos) x 64 co x 2 batches; 4 waves x 16 pos.
// grid (64 h, 2 bpair, nconv). D mapping: co = l15, pos = 4g+r.
// layouts: 0 = bf16 [n][co], 1 = bf16 [co][n], 2 = fp32 [co][n] (d_out)
// K-producing convs (1,3) get bias x log2(e) (weights already scaled).
// ---------------------------------------------------------------------------
__global__ __launch_bounds__(256) void conv_mfma_kernel(
    const unsigned short* __restrict__ xpad, const unsigned short* __restrict__ ypad,
    const unsigned short* __restrict__ rpadR, const unsigned short* __restrict__ rpadI,
    const unsigned short* __restrict__ Wf,
    const float* __restrict__ qb, const float* __restrict__ rkb,
    const float* __restrict__ rvb, const float* __restrict__ ikb,
    const float* __restrict__ ivb, const float* __restrict__ srb,
    unsigned short* __restrict__ Qt, unsigned short* __restrict__ KtR,
    unsigned short* __restrict__ VR, unsigned short* __restrict__ KtI,
    unsigned short* __restrict__ VI, float* __restrict__ outf,
    int convid_base)
{
    const int conv = convid_base + blockIdx.z;
    const int h = blockIdx.x, bp = blockIdx.y;
    const unsigned short *in0, *in1; const float* bias;
    int nsrc, wfbase, layout; void* outp;
    switch (conv) {
        case 0:  in0 = xpad;  in1 = ypad;  nsrc = 2; wfbase = 0;   bias = qb;  outp = Qt;  layout = 0; break;
        case 1:  in0 = xpad;  in1 = 0;     nsrc = 1; wfbase = 36;  bias = rkb; outp = KtR; layout = 0; break;
        case 2:  in0 = xpad;  in1 = 0;     nsrc = 1; wfbase = 54;  bias = rvb; outp = VR;  layout = 1; break;
        case 3:  in0 = ypad;  in1 = 0;     nsrc = 1; wfbase = 72;  bias = ikb; outp = KtI; layout = 0; break;
        case 4:  in0 = ypad;  in1 = 0;     nsrc = 1; wfbase = 90;  bias = ivb; outp = VI;  layout = 1; break;
        default: in0 = rpadR; in1 = rpadI; nsrc = 2; wfbase = 108; bias = srb; outp = outf; layout = 2; break;
    }
    const float bmul = (conv == 1 || conv == 3) ? LOG2E : 1.0f;
    const int lane = threadIdx.x & 63, wv = threadIdx.x >> 6;
    const int l15 = lane & 15, g = lane >> 4;

    f32x4_t acc[2][4];
#pragma unroll
    for (int bi = 0; bi < 2; ++bi)
#pragma unroll
        for (int i = 0; i < 4; ++i) acc[bi][i] = (f32x4_t){0.f, 0.f, 0.f, 0.f};

    int f = wfbase;
    for (int src = 0; src < nsrc; ++src) {
        const unsigned short* base0 = (src ? in1 : in0) + (size_t)(bp * 2) * PADN * CD;
        const unsigned short* base1 = base0 + (size_t)PADN * CD;
        for (int ky = 0; ky < 3; ++ky) {
            for (int kx = 0; kx < 3; ++kx) {
                const int pos = (h + ky) * PADW + wv * 16 + kx + l15;
                const unsigned short* ap0 = base0 + (size_t)pos * CD + g * 8;
                const unsigned short* ap1 = base1 + (size_t)pos * CD + g * 8;
#pragma unroll
                for (int kt = 0; kt < 2; ++kt, ++f) {
                    bf16x8_t a0 = *(const bf16x8_t*)(ap0 + kt * 32);
                    bf16x8_t a1 = *(const bf16x8_t*)(ap1 + kt * 32);
#pragma unroll
                    for (int cot = 0; cot < 4; ++cot) {
                        bf16x8_t bf = *(const bf16x8_t*)(Wf + ((size_t)(f * 4 + cot) * 64 + lane) * 8);
                        acc[0][cot] = __builtin_amdgcn_mfma_f32_16x16x32_bf16(a0, bf, acc[0][cot], 0, 0, 0);
                        acc[1][cot] = __builtin_amdgcn_mfma_f32_16x16x32_bf16(a1, bf, acc[1][cot], 0, 0, 0);
                    }
                }
            }
        }
    }

    const int nb4 = h * 64 + wv * 16 + g * 4;   // first of 4 consecutive n
#pragma unroll
    for (int bi = 0; bi < 2; ++bi) {
        const int b = bp * 2 + bi;
        if (layout == 0) {
            unsigned short* o = (unsigned short*)outp + (size_t)b * NPOS * CD;
#pragma unroll
            for (int cot = 0; cot < 4; ++cot) {
                const int co = cot * 16 + l15;
                const float bv = bias[co] * bmul;
#pragma unroll
                for (int r = 0; r < 4; ++r)
                    o[(size_t)(nb4 + r) * CD + co] = f2bf(fmaxf(acc[bi][cot][r] + bv, 0.f));
            }
        } else if (layout == 1) {
            unsigned short* o = (unsigned short*)outp + (size_t)b * CD * NPOS;
#pragma unroll
            for (int cot = 0; cot < 4; ++cot) {
                const int c = cot * 16 + l15;
                const float bv = bias[c];
                unsigned short us[4];
#pragma unroll
                for (int r = 0; r < 4; ++r) us[r] = f2bf(fmaxf(acc[bi][cot][r] + bv, 0.f));
                *(uint2*)(o + (size_t)c * NPOS + nb4) = *(uint2*)us;
            }
        } else {
            float* o = (float*)outp + (size_t)b * CD * NPOS;
#pragma unroll
            for (int cot = 0; cot < 4; ++cot) {
                const int c = cot * 16 + l15;
                const float bv = bias[c];
                f32x4_t v;
#pragma unroll
                for (int r = 0; r < 4; ++r) v[r] = fmaxf(acc[bi][cot][r] + bv, 0.f);
                *(f32x4_t*)(o + (size_t)c * NPOS + nb4) = v;
            }
        }
    }
}

// ---------------------------------------------------------------------------
// Flash attention over an n-segment (base-2 softmax, defer-max, pipelined V).
//   Qt/Kt bf16 [b][n][64]; V bf16 [b][c][n]. K pre-scaled by log2(e).
// 1024 blocks (flat): fid&1=att, (fid>>1)&3=b, (fid>>3)&1=seg, fid>>4=mblk.
//   -> fid%8 = (b,att) group => each XCD's L2 keeps one 1.5MB Q/K/V set.
// block 256 = 4 waves x 16 m rows. V double-buffered in LDS via
// global_load_lds; counted vmcnt(2) + raw s_barrier keeps next-tile DMA in
// flight across the barrier. Q A-frags direct from global (L1-shared).
// Opart fp32 [att][b][seg][m][c]; ml fp32 [att][b][seg][m][2] (base-2 m, l).
// ---------------------------------------------------------------------------
__global__ __launch_bounds__(256) void attn_kernel(
    const unsigned short* __restrict__ Qt,
    const unsigned short* __restrict__ KtR, const unsigned short* __restrict__ KtI,
    const unsigned short* __restrict__ VR,  const unsigned short* __restrict__ VI,
    float* __restrict__ Opart, float* __restrict__ ml)
{
    const int fid = blockIdx.x;
    const int att = fid & 1;
    const int b   = (fid >> 1) & 3;
    const int seg = (fid >> 3) & 1;
    const int mblk = fid >> 4;
    const int lane = threadIdx.x & 63, wv = threadIdx.x >> 6;
    const int l15 = lane & 15, g = lane >> 4;
    const int m0 = mblk * 64 + wv * 16;

    const unsigned short* Qb = Qt + (size_t)b * NPOS * CD;
    const unsigned short* Kb = (att ? KtI : KtR) + (size_t)b * NPOS * CD;
    const unsigned short* Vb = (att ? VI : VR) + (size_t)b * CD * NPOS;

    __shared__ unsigned short Vs[2][64 * 64];
    __shared__ unsigned short plds[4][16 * 68];
    unsigned short* pl = plds[wv];

    // K fragments (B operand: col=m=l15, k=d), persistent for whole kernel
    const bf16x8_t bK0 = *(const bf16x8_t*)&Kb[(size_t)(m0 + l15) * CD + g * 8];
    const bf16x8_t bK1 = *(const bf16x8_t*)&Kb[(size_t)(m0 + l15) * CD + 32 + g * 8];

    f32x4_t O[4];
#pragma unroll
    for (int i = 0; i < 4; ++i) O[i] = (f32x4_t){0.f, 0.f, 0.f, 0.f};
    float mrun = -3.0e38f, lsum = 0.f;   // lsum: per-lane partial

    const int csw = (lane & 7) ^ ((lane >> 3) & 7);   // swizzled source chunk
    const int sx = l15 & 7;                            // read-side XOR key
    const int nbase = seg * (NPOS / NSEG);

    // stage one 64c x 64n V tile (8KB): 2 global_load_lds per thread
#define STAGE_V(n0v, buf) do {                                                \
        _Pragma("unroll")                                                     \
        for (int j = 0; j < 2; ++j) {                                         \
            const int r_ = wv * 16 + j * 8 + (lane >> 3);                     \
            gload_lds16(Vb + (size_t)r_ * NPOS + (n0v) + csw * 8,             \
                        &Vs[buf][(wv * 16 + j * 8) * 64]);                    \
        }                                                                     \
    } while (0)

    STAGE_V(nbase, 0);

    for (int it = 0; it < NT; ++it) {
        const int cur = it & 1;
        const int n0 = nbase + it * 64;
        // ---- Q A-frags first (latency-critical) ----
        bf16x8_t qa0[4], qa1[4];
#pragma unroll
        for (int nt = 0; nt < 4; ++nt) {
            const unsigned short* qp = &Qb[(size_t)(n0 + nt * 16 + l15) * CD + g * 8];
            qa0[nt] = *(const bf16x8_t*)qp;
            qa1[nt] = *(const bf16x8_t*)(qp + 32);
        }
        // ---- DMA next V tile (dummy on last iter keeps vmcnt invariant) ----
        STAGE_V(it + 1 < NT ? n0 + 64 : nbase, cur ^ 1);

        // ---- QK^T: St[row=n_local, col=m] ----
        f32x4_t St[4];
        __builtin_amdgcn_s_setprio(1);
#pragma unroll
        for (int nt = 0; nt < 4; ++nt) {
            f32x4_t c = (f32x4_t){0.f, 0.f, 0.f, 0.f};
            c = __builtin_amdgcn_mfma_f32_16x16x32_bf16(qa0[nt], bK0, c, 0, 0, 0);
            c = __builtin_amdgcn_mfma_f32_16x16x32_bf16(qa1[nt], bK1, c, 0, 0, 0);
            St[nt] = c;
        }
        __builtin_amdgcn_s_setprio(0);

        // ---- online softmax, base-2, defer-max (lane's 16 vals share m) ----
        float t0 = fmaxf(fmaxf(St[0][0], St[0][1]), fmaxf(St[0][2], St[0][3]));
        float t1 = fmaxf(fmaxf(St[1][0], St[1][1]), fmaxf(St[1][2], St[1][3]));
        float t2 = fmaxf(fmaxf(St[2][0], St[2][1]), fmaxf(St[2][2], St[2][3]));
        float t3 = fmaxf(fmaxf(St[3][0], St[3][1]), fmaxf(St[3][2], St[3][3]));
        const float tmax = fmaxf(fmaxf(t0, t1), fmaxf(t2, t3));
        if (!__all(tmax <= mrun + 12.0f)) {
            float tr = fmaxf(tmax, __shfl_xor(tmax, 16));
            tr = fmaxf(tr, __shfl_xor(tr, 32));
            const float mnew = fmaxf(mrun, tr);
            const float corr = __ocml_exp2_f32(mrun - mnew);
            lsum *= corr;
#pragma unroll
            for (int i = 0; i < 4; ++i) {
                O[i][0] *= corr; O[i][1] *= corr; O[i][2] *= corr; O[i][3] *= corr;
            }
            mrun = mnew;
        }
        unsigned int pw[8];
#pragma unroll
        for (int nt = 0; nt < 4; ++nt) {
            float p0 = __ocml_exp2_f32(St[nt][0] - mrun);
            float p1 = __ocml_exp2_f32(St[nt][1] - mrun);
            float p2 = __ocml_exp2_f32(St[nt][2] - mrun);
            float p3 = __ocml_exp2_f32(St[nt][3] - mrun);
            lsum += (p0 + p1) + (p2 + p3);
            pw[nt * 2 + 0] = (unsigned)f2bf(p0) | ((unsigned)f2bf(p1) << 16);
            pw[nt * 2 + 1] = (unsigned)f2bf(p2) | ((unsigned)f2bf(p3) << 16);
        }
        // ---- P -> per-wave LDS (linear in n at row m=l15) ----
#pragma unroll
        for (int nt = 0; nt < 4; ++nt)
            *(uint2*)&pl[l15 * 68 + nt * 16 + g * 4] =
                make_uint2(pw[nt * 2], pw[nt * 2 + 1]);

        // ---- barrier with counted vmcnt: old DMAs (Vs[cur]) done, new stay ----
        asm volatile("s_waitcnt vmcnt(2)" ::: "memory");
        __builtin_amdgcn_sched_barrier(0);
        __builtin_amdgcn_s_barrier();
        __builtin_amdgcn_sched_barrier(0);

        // ---- PV: O[c,m] += V[c,:] P[m,:] ----
        __builtin_amdgcn_s_setprio(1);
#pragma unroll
        for (int nc = 0; nc < 2; ++nc) {
            union { bf16x8_t v; uint2 d2[2]; } bp;
            bp.d2[0] = *(uint2*)&pl[l15 * 68 + nc * 32 + g * 8];
            bp.d2[1] = *(uint2*)&pl[l15 * 68 + nc * 32 + g * 8 + 4];
#pragma unroll
            for (int ct = 0; ct < 4; ++ct) {
                bf16x8_t av = *(const bf16x8_t*)
                    (&Vs[cur][(ct * 16 + l15) * 64 + (((nc * 4 + g) ^ sx) * 8)]);
                O[ct] = __builtin_amdgcn_mfma_f32_16x16x32_bf16(av, bp.v, O[ct], 0, 0, 0);
            }
        }
        __builtin_amdgcn_s_setprio(0);
        __builtin_amdgcn_s_barrier();     // protect Vs[cur] from next iter's DMA
        __builtin_amdgcn_sched_barrier(0);
    }
    asm volatile("s_waitcnt vmcnt(0)" ::: "memory");   // drain dummy DMA

    // ---- epilogue: reduce lsum across g, write partials ----
    float lred = lsum + __shfl_xor(lsum, 16);
    lred += __shfl_xor(lred, 32);
    float* Ob = Opart + ((((size_t)att * NB + b) * NSEG + seg) * NPOS) * CD;
    const int m = m0 + l15;
#pragma unroll
    for (int ct = 0; ct < 4; ++ct)
        *(f32x4_t*)(Ob + (size_t)m * CD + ct * 16 + g * 4) = O[ct];
    if (g == 0) {
        float* mlb = ml + ((((size_t)att * NB + b) * NSEG + seg) * NPOS + m) * 2;
        mlb[0] = mrun; mlb[1] = lred;
    }
#undef STAGE_V
}

// ---------------------------------------------------------------------------
// Combine NSEG partials -> refine = gamma*O/L + resid, bf16 into padded
// layout for the SR conv. grid (64 mtile, NB, 2 att). Base-2 weights.
// ---------------------------------------------------------------------------
__global__ __launch_bounds__(256) void combine_kernel(
    const float* __restrict__ Opart, const float* __restrict__ ml,
    const float* __restrict__ x, const float* __restrict__ y,
    const float* __restrict__ g1, const float* __restrict__ g2,
    unsigned short* __restrict__ rpadR, unsigned short* __restrict__ rpadI)
{
    const int mt = blockIdx.x, b = blockIdx.y, att = blockIdx.z;
    const float* resid = att ? x : y;
    const float gamma = att ? g2[0] : g1[0];
    unsigned short* rp = (att ? rpadI : rpadR) + (size_t)b * PADN * CD;
    __shared__ float t[64][65];
    const int tt = threadIdx.x;
    {
        const int c = tt >> 2, w0 = (tt & 3) * 16;
        const float* p = resid + ((size_t)b * CD + c) * NPOS + mt * 64 + w0;
#pragma unroll
        for (int j = 0; j < 16; j += 4) {
            float4 v = *(const float4*)(p + j);
            t[c][w0 + j] = v.x; t[c][w0 + j + 1] = v.y;
            t[c][w0 + j + 2] = v.z; t[c][w0 + j + 3] = v.w;
        }
    }
    __syncthreads();
    const int c = tt & 63, mq = tt >> 6;
    const size_t ob = (((size_t)att * NB + b) * NSEG) * NPOS * CD;
    const size_t mb = (((size_t)att * NB + b) * NSEG) * NPOS;
    for (int p = 0; p < 16; ++p) {
        const int mloc = mq * 16 + p;
        const int m = mt * 64 + mloc;
        float mm[NSEG], llv[NSEG];
#pragma unroll
        for (int s = 0; s < NSEG; ++s) {
            mm[s] = ml[(mb + (size_t)s * NPOS + m) * 2];
            llv[s] = ml[(mb + (size_t)s * NPOS + m) * 2 + 1];
        }
        float M = mm[0];
#pragma unroll
        for (int s = 1; s < NSEG; ++s) M = fmaxf(M, mm[s]);
        float Ov = 0.f, L = 0.f;
#pragma unroll
        for (int s = 0; s < NSEG; ++s) {
            const float wgt = __ocml_exp2_f32(mm[s] - M);
            L += wgt * llv[s];
            Ov += wgt * Opart[ob + ((size_t)s * NPOS + m) * CD + c];
        }
        const float val = fmaf(gamma, Ov / L, t[c][mloc]);
        const int h = m >> 6, w_ = m & 63;
        rp[((size_t)((h + 1) * PADW) + (w_ + 1)) * CD + c] = f2bf(val);
    }
}

// ---------------------------------------------------------------------------
extern "C" void kernel_launch(void* const* d_in, const int* in_sizes, int n_in,
                              void* d_out, int out_size, void* d_ws, size_t ws_size,
                              hipStream_t stream)
{
    const float* x    = (const float*)d_in[0];
    const float* y    = (const float*)d_in[1];
    const float* q_w  = (const float*)d_in[2];
    const float* q_s  = (const float*)d_in[3];
    const float* q_b  = (const float*)d_in[4];
    const float* rk_w = (const float*)d_in[5];
    const float* rk_s = (const float*)d_in[6];
    const float* rk_b = (const float*)d_in[7];
    const float* rv_w = (const float*)d_in[8];
    const float* rv_s = (const float*)d_in[9];
    const float* rv_b = (const float*)d_in[10];
    const float* ik_w = (const float*)d_in[11];
    const float* ik_s = (const float*)d_in[12];
    const float* ik_b = (const float*)d_in[13];
    const float* iv_w = (const float*)d_in[14];
    const float* iv_s = (const float*)d_in[15];
    const float* iv_b = (const float*)d_in[16];
    const float* sr_w = (const float*)d_in[17];
    const float* sr_s = (const float*)d_in[18];
    const float* sr_b = (const float*)d_in[19];
    const float* g1   = (const float*)d_in[20];
    const float* g2   = (const float*)d_in[21];

    char* ws = (char*)d_ws;
    size_t off = 0;
    auto alloc = [&](size_t bytes) {
        void* p = ws + off; off += (bytes + 255) & ~(size_t)255; return p;
    };
    const size_t PADB = (size_t)NB * PADN * CD * 2;
    unsigned short* xpad  = (unsigned short*)alloc(PADB);
    unsigned short* ypad  = (unsigned short*)alloc(PADB);
    unsigned short* rpadR = (unsigned short*)alloc(PADB);
    unsigned short* rpadI = (unsigned short*)alloc(PADB);
    unsigned short* Qt  = (unsigned short*)alloc((size_t)NB * NPOS * CD * 2);
    unsigned short* KtR = (unsigned short*)alloc((size_t)NB * NPOS * CD * 2);
    unsigned short* KtI = (unsigned short*)alloc((size_t)NB * NPOS * CD * 2);
    unsigned short* VR  = (unsigned short*)alloc((size_t)NB * NPOS * CD * 2);
    unsigned short* VI  = (unsigned short*)alloc((size_t)NB * NPOS * CD * 2);
    unsigned short* Wf  = (unsigned short*)alloc((size_t)144 * 4 * 64 * 16);
    float* Opart = (float*)alloc((size_t)2 * NB * NSEG * NPOS * CD * 4);
    float* mlb   = (float*)alloc((size_t)2 * NB * NSEG * NPOS * 2 * 4);

    // prep: halo-zero + weight repack + input pack (one launch, no memset)
    prep_kernel<<<dim3(672), 256, 0, stream>>>(
        x, y, q_w, rk_w, rv_w, ik_w, iv_w, sr_w,
        q_s, rk_s, rv_s, ik_s, iv_s, sr_s, xpad, Wf);
    // 5 pre-attention convs, 2 batches per block
    conv_mfma_kernel<<<dim3(64, 2, 5), 256, 0, stream>>>(
        xpad, ypad, rpadR, rpadI, Wf,
        q_b, rk_b, rv_b, ik_b, iv_b, sr_b,
        Qt, KtR, VR, KtI, VI, nullptr, 0);
    attn_kernel<<<dim3(64 * NB * 2 * NSEG), 256, 0, stream>>>(
        Qt, KtR, KtI, VR, VI, Opart, mlb);
    combine_kernel<<<dim3(64, NB, 2), 256, 0, stream>>>(
        Opart, mlb, x, y, g1, g2, rpadR, rpadI);
    // final SR conv -> d_out fp32 NCHW
    conv_mfma_kernel<<<dim3(64, 2, 1), 256, 0, stream>>>(
        xpad, ypad, rpadR, rpadI, Wf,
        q_b, rk_b, rv_b, ik_b, iv_b, sr_b,
        Qt, KtR, VR, KtI, VI, (float*)d_out, 5);
}

// Round 5
// 233.119 us; speedup vs baseline: 1.3370x; 1.3370x over previous
//
#include <hip/hip_runtime.h>
#include <hip/hip_bf16.h>

#define NPOS 4096          // 64*64 positions
#define CD   64            // channels
#define NB   4             // batch
#define PADW 66
#define PADN (66*66)       // padded positions (zero halo)
#define NSEG 4             // attention n-split
#define NT   (NPOS / NSEG / 64)
#define LOG2E 1.4426950408889634f

extern "C" __device__ float __ocml_exp2_f32(float);

typedef __bf16 bf16x8_t __attribute__((ext_vector_type(8)));
typedef float  f32x4_t  __attribute__((ext_vector_type(4)));

static __device__ __forceinline__ unsigned short f2bf(float f) {
    return __builtin_bit_cast(unsigned short, __float2bfloat16(f));
}

static __device__ __forceinline__ void gload_lds16(const void* g, void* l) {
    __builtin_amdgcn_global_load_lds(
        (const __attribute__((address_space(1))) void*)g,
        (__attribute__((address_space(3))) void*)l, 16, 0, 0);
}

// ---------------------------------------------------------------------------
// prep: fused {halo-zero, weight-repack, input-pack} in one launch.
// grid 672 = 16 halo + 144 wrepack + 512 pack. block 256.
// ---------------------------------------------------------------------------
__global__ __launch_bounds__(256) void prep_kernel(
    const float* __restrict__ x, const float* __restrict__ y,
    const float* __restrict__ qw, const float* __restrict__ rkw,
    const float* __restrict__ rvw, const float* __restrict__ ikw,
    const float* __restrict__ ivw, const float* __restrict__ srw,
    const float* __restrict__ qs, const float* __restrict__ rks,
    const float* __restrict__ rvs, const float* __restrict__ iks,
    const float* __restrict__ ivs, const float* __restrict__ srs,
    unsigned short* __restrict__ pads, unsigned short* __restrict__ Wf)
{
    const int bx = blockIdx.x;
    if (bx < 16) {
        // ---- halo zero: image bx of the 16 contiguous padded images ----
        unsigned short* p = pads + (size_t)bx * PADN * CD;
        const uint4 z = make_uint4(0, 0, 0, 0);
        for (int idx = threadIdx.x; idx < 260 * 8; idx += 256) {
            const int pi = idx >> 3, chn = idx & 7;
            int pos;
            if (pi < 66)       pos = pi;
            else if (pi < 132) pos = 65 * PADW + (pi - 66);
            else { const int rem = pi - 132;
                   pos = (1 + (rem >> 1)) * PADW + ((rem & 1) ? 65 : 0); }
            *(uint4*)(p + (size_t)pos * CD + chn * 8) = z;
        }
        return;
    }
    if (bx < 160) {
        // ---- weight repack, f = bx-16 in [0,144) ----
        const int f = bx - 16;
        const float* w; const float* s; int cin, local;
        if (f < 36)       { w = qw;  s = qs;  cin = 128; local = f; }
        else if (f < 54)  { w = rkw; s = rks; cin = 64;  local = f - 36; }
        else if (f < 72)  { w = rvw; s = rvs; cin = 64;  local = f - 54; }
        else if (f < 90)  { w = ikw; s = iks; cin = 64;  local = f - 72; }
        else if (f < 108) { w = ivw; s = ivs; cin = 64;  local = f - 90; }
        else              { w = srw; s = srs; cin = 128; local = f - 108; }
        const int src = (cin == 128) ? local / 18 : 0;
        const int rem = (cin == 128) ? local % 18 : local;
        const int tap = rem >> 1, kt = rem & 1;
        const int t = threadIdx.x, cot = t >> 6, l = t & 63;
        const int co = cot * 16 + (l & 15);
        const float kmul = ((f >= 36 && f < 54) || (f >= 72 && f < 90)) ? LOG2E : 1.0f;
        const float sc = s[co] * kmul;
        unsigned short us[8];
#pragma unroll
        for (int e = 0; e < 8; ++e) {
            const int ci = src * 64 + kt * 32 + ((l >> 4) * 8) + e;
            us[e] = f2bf(w[((size_t)co * cin + ci) * 9 + tap] * sc);
        }
        *(uint4*)(Wf + ((size_t)(f * 4 + cot) * 64 + l) * 8) = *(uint4*)us;
        return;
    }
    // ---- pack: idx = bx-160 in [0,512): h, b, src ----
    {
        const int idx = bx - 160;
        const int h = idx & 63, b = (idx >> 6) & 3, src = idx >> 8;
        const float* in = src ? y : x;
        unsigned short* out = pads + (size_t)src * NB * PADN * CD;  // xpad or ypad
        __shared__ float t[64][65];
        const int tt = threadIdx.x;
        {
            const int ci = tt >> 2, w0 = (tt & 3) * 16;
            const float* p = in + ((size_t)b * 64 + ci) * NPOS + h * 64 + w0;
#pragma unroll
            for (int j = 0; j < 16; j += 4) {
                float4 v = *(const float4*)(p + j);
                t[ci][w0 + j] = v.x; t[ci][w0 + j + 1] = v.y;
                t[ci][w0 + j + 2] = v.z; t[ci][w0 + j + 3] = v.w;
            }
        }
        __syncthreads();
        const int w = tt >> 2, c0 = (tt & 3) * 16;
        unsigned short us[16];
#pragma unroll
        for (int j = 0; j < 16; ++j) us[j] = f2bf(t[c0 + j][w]);
        unsigned short* q = out + ((size_t)b * PADN + (h + 1) * PADW + (w + 1)) * CD + c0;
        *(uint4*)q = *(uint4*)us;
        *(uint4*)(q + 8) = *(uint4*)(us + 8);
    }
}

// ---------------------------------------------------------------------------
// Implicit-GEMM conv3x3 via MFMA, weight frags staged in LDS per (src,ky)
// chunk (12 slots x 1KB, lane-contiguous ds_read_b128 = conflict-free).
// Block = one h row (64 pos) x 32 co (co-half) x 1 batch; 4 waves x 16 pos.
// grid (64 h, NB, 2*nconv): z>>1 = conv (+base), z&1 = co half.
// D mapping: co = (ch*2+cc)*16 + l15, pos = 4g+r.
// layouts: 0 = bf16 [n][co], 1 = bf16 [co][n], 2 = fp32 [co][n] (d_out)
// K-producing convs (1,3) get bias x log2(e) (weights already scaled).
// ---------------------------------------------------------------------------
__global__ __launch_bounds__(256) void conv_mfma_kernel(
    const unsigned short* __restrict__ xpad, const unsigned short* __restrict__ ypad,
    const unsigned short* __restrict__ rpadR, const unsigned short* __restrict__ rpadI,
    const unsigned short* __restrict__ Wf,
    const float* __restrict__ qb, const float* __restrict__ rkb,
    const float* __restrict__ rvb, const float* __restrict__ ikb,
    const float* __restrict__ ivb, const float* __restrict__ srb,
    unsigned short* __restrict__ Qt, unsigned short* __restrict__ KtR,
    unsigned short* __restrict__ VR, unsigned short* __restrict__ KtI,
    unsigned short* __restrict__ VI, float* __restrict__ outf,
    int convid_base)
{
    const int conv = convid_base + (blockIdx.z >> 1);
    const int ch   = blockIdx.z & 1;            // co half
    const int h = blockIdx.x, b = blockIdx.y;
    const unsigned short *in0, *in1; const float* bias;
    int nsrc, wfbase, layout; void* outp;
    switch (conv) {
        case 0:  in0 = xpad;  in1 = ypad;  nsrc = 2; wfbase = 0;   bias = qb;  outp = Qt;  layout = 0; break;
        case 1:  in0 = xpad;  in1 = 0;     nsrc = 1; wfbase = 36;  bias = rkb; outp = KtR; layout = 0; break;
        case 2:  in0 = xpad;  in1 = 0;     nsrc = 1; wfbase = 54;  bias = rvb; outp = VR;  layout = 1; break;
        case 3:  in0 = ypad;  in1 = 0;     nsrc = 1; wfbase = 72;  bias = ikb; outp = KtI; layout = 0; break;
        case 4:  in0 = ypad;  in1 = 0;     nsrc = 1; wfbase = 90;  bias = ivb; outp = VI;  layout = 1; break;
        default: in0 = rpadR; in1 = rpadI; nsrc = 2; wfbase = 108; bias = srb; outp = outf; layout = 2; break;
    }
    const float bmul = (conv == 1 || conv == 3) ? LOG2E : 1.0f;
    const int lane = threadIdx.x & 63, wv = threadIdx.x >> 6;
    const int l15 = lane & 15, g = lane >> 4;

    __shared__ unsigned short Wl[12 * 512];   // 12 slots x 1KB

    f32x4_t acc[2];
    acc[0] = (f32x4_t){0.f, 0.f, 0.f, 0.f};
    acc[1] = (f32x4_t){0.f, 0.f, 0.f, 0.f};

    const int nchunk = nsrc * 3;
    for (int c = 0; c < nchunk; ++c) {
        const int src = (c >= 3) ? 1 : 0;
        const int ky  = c - src * 3;
        if (c) __syncthreads();               // protect prev-chunk reads
        // ---- stage 12 Wf slots (wave wv stages slots wv*3..wv*3+2) ----
#pragma unroll
        for (int j = 0; j < 3; ++j) {
            const int slot = wv * 3 + j;
            const int fj = slot >> 1, cotl = slot & 1;
            const int fg = wfbase + c * 6 + fj;
            gload_lds16(Wf + ((size_t)(fg * 4 + ch * 2 + cotl) * 64 + lane) * 8,
                        Wl + slot * 512);
        }
        __syncthreads();                      // stage visible (vmcnt drained)
        // ---- compute: 6 A-frags x 2 cot MFMAs from LDS weights ----
        const unsigned short* base = (src ? in1 : in0) + (size_t)b * PADN * CD;
#pragma unroll
        for (int kx = 0; kx < 3; ++kx) {
            const int pos = (h + ky) * PADW + wv * 16 + kx + l15;
            const unsigned short* ap = base + (size_t)pos * CD + g * 8;
#pragma unroll
            for (int kt = 0; kt < 2; ++kt) {
                bf16x8_t a = *(const bf16x8_t*)(ap + kt * 32);
                const int fj = kx * 2 + kt;
#pragma unroll
                for (int cc = 0; cc < 2; ++cc) {
                    bf16x8_t bfr = *(const bf16x8_t*)(Wl + (size_t)(fj * 2 + cc) * 512 + lane * 8);
                    acc[cc] = __builtin_amdgcn_mfma_f32_16x16x32_bf16(a, bfr, acc[cc], 0, 0, 0);
                }
            }
        }
    }

    const int nb4 = h * 64 + wv * 16 + g * 4;   // first of 4 consecutive n
    if (layout == 0) {
        unsigned short* o = (unsigned short*)outp + (size_t)b * NPOS * CD;
#pragma unroll
        for (int cc = 0; cc < 2; ++cc) {
            const int co = (ch * 2 + cc) * 16 + l15;
            const float bv = bias[co] * bmul;
#pragma unroll
            for (int r = 0; r < 4; ++r)
                o[(size_t)(nb4 + r) * CD + co] = f2bf(fmaxf(acc[cc][r] + bv, 0.f));
        }
    } else if (layout == 1) {
        unsigned short* o = (unsigned short*)outp + (size_t)b * CD * NPOS;
#pragma unroll
        for (int cc = 0; cc < 2; ++cc) {
            const int cch = (ch * 2 + cc) * 16 + l15;
            const float bv = bias[cch];
            unsigned short us[4];
#pragma unroll
            for (int r = 0; r < 4; ++r) us[r] = f2bf(fmaxf(acc[cc][r] + bv, 0.f));
            *(uint2*)(o + (size_t)cch * NPOS + nb4) = *(uint2*)us;
        }
    } else {
        float* o = (float*)outp + (size_t)b * CD * NPOS;
#pragma unroll
        for (int cc = 0; cc < 2; ++cc) {
            const int cch = (ch * 2 + cc) * 16 + l15;
            const float bv = bias[cch];
            f32x4_t v;
#pragma unroll
            for (int r = 0; r < 4; ++r) v[r] = fmaxf(acc[cc][r] + bv, 0.f);
            *(f32x4_t*)(o + (size_t)cch * NPOS + nb4) = v;
        }
    }
}

// ---------------------------------------------------------------------------
// Flash attention over an n-segment (base-2 softmax, defer-max).
//   Qt/Kt bf16 [b][n][64]; V bf16 [b][c][n]. K pre-scaled by log2(e).
// 2048 blocks: fid&1=att, (fid>>1)&3=b (fid&7 = XCD group), (fid>>3)&3=seg,
// mblk=fid>>5. block 256 = 4 waves x 16 m rows.
// Q+V tiles double-buffered in LDS via global_load_lds (XOR chunk swizzle on
// the GLOBAL source; linear LDS dest; same XOR on reads). ONE __syncthreads
// per iter; stage(next) issued right after it so DMA overlaps QK+softmax+PV.
// Opart fp32 [att][b][seg][m][c]; ml fp32 [att][b][seg][m][2] (base-2 m, l).
// ---------------------------------------------------------------------------
__global__ __launch_bounds__(256) void attn_kernel(
    const unsigned short* __restrict__ Qt,
    const unsigned short* __restrict__ KtR, const unsigned short* __restrict__ KtI,
    const unsigned short* __restrict__ VR,  const unsigned short* __restrict__ VI,
    float* __restrict__ Opart, float* __restrict__ ml)
{
    const int fid = blockIdx.x;
    const int att = fid & 1;
    const int b   = (fid >> 1) & 3;
    const int seg = (fid >> 3) & 3;
    const int mblk = fid >> 5;
    const int lane = threadIdx.x & 63, wv = threadIdx.x >> 6;
    const int l15 = lane & 15, g = lane >> 4;
    const int m0 = mblk * 64 + wv * 16;

    const unsigned short* Qb = Qt + (size_t)b * NPOS * CD;
    const unsigned short* Kb = (att ? KtI : KtR) + (size_t)b * NPOS * CD;
    const unsigned short* Vb = (att ? VI : VR) + (size_t)b * CD * NPOS;

    __shared__ unsigned short Qs[2][64 * 64];
    __shared__ unsigned short Vs[2][64 * 64];
    __shared__ unsigned short plds[4][16 * 68];
    unsigned short* pl = plds[wv];

    // K fragments (B operand: col=m=l15, k=d), persistent for whole kernel
    const bf16x8_t bK0 = *(const bf16x8_t*)&Kb[(size_t)(m0 + l15) * CD + g * 8];
    const bf16x8_t bK1 = *(const bf16x8_t*)&Kb[(size_t)(m0 + l15) * CD + 32 + g * 8];

    f32x4_t O[4];
#pragma unroll
    for (int i = 0; i < 4; ++i) O[i] = (f32x4_t){0.f, 0.f, 0.f, 0.f};
    float mrun = -3.0e38f, lsum = 0.f;   // lsum: per-lane partial

    const int csw = (lane & 7) ^ ((lane >> 3) & 7);   // swizzled source chunk
    const int sx = l15 & 7;                            // read-side XOR key
    const int nbase = seg * (NPOS / NSEG);

    // stage one 64x64 Q tile + 64x64 V tile (16KB): 4 gload_lds per thread
#define STAGE(buf, n0v) do {                                                  \
        _Pragma("unroll")                                                     \
        for (int j = 0; j < 2; ++j) {                                         \
            const int rq = wv * 16 + j * 8 + (lane >> 3);                     \
            gload_lds16(Qb + (size_t)(n0v + rq) * CD + csw * 8,               \
                        &Qs[buf][(wv * 16 + j * 8) * 64]);                    \
            gload_lds16(Vb + (size_t)rq * NPOS + (n0v) + csw * 8,             \
                        &Vs[buf][(wv * 16 + j * 8) * 64]);                    \
        }                                                                     \
    } while (0)

    STAGE(0, nbase);

    for (int it = 0; it < NT; ++it) {
        const int cur = it & 1;
        const int n0 = nbase + it * 64;
        __syncthreads();   // drains stage(cur) DMAs; prev-iter reads done
        if (it + 1 < NT) STAGE(cur ^ 1, n0 + 64);   // overlaps compute below

        // ---- QK^T: St[row=n_local, col=m] ----
        f32x4_t St[4];
        __builtin_amdgcn_s_setprio(1);
#pragma unroll
        for (int nt = 0; nt < 4; ++nt) {
            const unsigned short* qr = &Qs[cur][(nt * 16 + l15) * 64];
            bf16x8_t a0 = *(const bf16x8_t*)(qr + (g ^ sx) * 8);
            bf16x8_t a1 = *(const bf16x8_t*)(qr + ((4 + g) ^ sx) * 8);
            f32x4_t c = (f32x4_t){0.f, 0.f, 0.f, 0.f};
            c = __builtin_amdgcn_mfma_f32_16x16x32_bf16(a0, bK0, c, 0, 0, 0);
            c = __builtin_amdgcn_mfma_f32_16x16x32_bf16(a1, bK1, c, 0, 0, 0);
            St[nt] = c;
        }
        __builtin_amdgcn_s_setprio(0);

        // ---- online softmax, base-2, defer-max (lane's 16 vals share m) ----
        float t0 = fmaxf(fmaxf(St[0][0], St[0][1]), fmaxf(St[0][2], St[0][3]));
        float t1 = fmaxf(fmaxf(St[1][0], St[1][1]), fmaxf(St[1][2], St[1][3]));
        float t2 = fmaxf(fmaxf(St[2][0], St[2][1]), fmaxf(St[2][2], St[2][3]));
        float t3 = fmaxf(fmaxf(St[3][0], St[3][1]), fmaxf(St[3][2], St[3][3]));
        const float tmax = fmaxf(fmaxf(t0, t1), fmaxf(t2, t3));
        if (!__all(tmax <= mrun + 12.0f)) {
            float tr = fmaxf(tmax, __shfl_xor(tmax, 16));
            tr = fmaxf(tr, __shfl_xor(tr, 32));
            const float mnew = fmaxf(mrun, tr);
            const float corr = __ocml_exp2_f32(mrun - mnew);
            lsum *= corr;
#pragma unroll
            for (int i = 0; i < 4; ++i) {
                O[i][0] *= corr; O[i][1] *= corr; O[i][2] *= corr; O[i][3] *= corr;
            }
            mrun = mnew;
        }
        unsigned int pw[8];
#pragma unroll
        for (int nt = 0; nt < 4; ++nt) {
            float p0 = __ocml_exp2_f32(St[nt][0] - mrun);
            float p1 = __ocml_exp2_f32(St[nt][1] - mrun);
            float p2 = __ocml_exp2_f32(St[nt][2] - mrun);
            float p3 = __ocml_exp2_f32(St[nt][3] - mrun);
            lsum += (p0 + p1) + (p2 + p3);
            pw[nt * 2 + 0] = (unsigned)f2bf(p0) | ((unsigned)f2bf(p1) << 16);
            pw[nt * 2 + 1] = (unsigned)f2bf(p2) | ((unsigned)f2bf(p3) << 16);
        }
        // ---- P -> per-wave LDS (no barrier needed) ----
#pragma unroll
        for (int nt = 0; nt < 4; ++nt)
            *(uint2*)&pl[l15 * 68 + nt * 16 + g * 4] =
                make_uint2(pw[nt * 2], pw[nt * 2 + 1]);

        // ---- PV: O[c,m] += V[c,:] P[m,:] ----
        __builtin_amdgcn_s_setprio(1);
#pragma unroll
        for (int nc = 0; nc < 2; ++nc) {
            union { bf16x8_t v; uint2 d2[2]; } bp;
            bp.d2[0] = *(uint2*)&pl[l15 * 68 + nc * 32 + g * 8];
            bp.d2[1] = *(uint2*)&pl[l15 * 68 + nc * 32 + g * 8 + 4];
#pragma unroll
            for (int ct = 0; ct < 4; ++ct) {
                bf16x8_t av = *(const bf16x8_t*)
                    (&Vs[cur][(ct * 16 + l15) * 64 + (((nc * 4 + g) ^ sx) * 8)]);
                O[ct] = __builtin_amdgcn_mfma_f32_16x16x32_bf16(av, bp.v, O[ct], 0, 0, 0);
            }
        }
        __builtin_amdgcn_s_setprio(0);
    }

    // ---- epilogue: reduce lsum across g, write partials ----
    float lred = lsum + __shfl_xor(lsum, 16);
    lred += __shfl_xor(lred, 32);
    float* Ob = Opart + ((((size_t)att * NB + b) * NSEG + seg) * NPOS) * CD;
    const int m = m0 + l15;
#pragma unroll
    for (int ct = 0; ct < 4; ++ct)
        *(f32x4_t*)(Ob + (size_t)m * CD + ct * 16 + g * 4) = O[ct];
    if (g == 0) {
        float* mlb = ml + ((((size_t)att * NB + b) * NSEG + seg) * NPOS + m) * 2;
        mlb[0] = mrun; mlb[1] = lred;
    }
#undef STAGE
}

// ---------------------------------------------------------------------------
// Combine NSEG partials -> refine = gamma*O/L + resid, bf16 into padded
// layout for the SR conv. grid (64 mtile, NB, 2 att). Base-2 weights.
// ---------------------------------------------------------------------------
__global__ __launch_bounds__(256) void combine_kernel(
    const float* __restrict__ Opart, const float* __restrict__ ml,
    const float* __restrict__ x, const float* __restrict__ y,
    const float* __restrict__ g1, const float* __restrict__ g2,
    unsigned short* __restrict__ rpadR, unsigned short* __restrict__ rpadI)
{
    const int mt = blockIdx.x, b = blockIdx.y, att = blockIdx.z;
    const float* resid = att ? x : y;
    const float gamma = att ? g2[0] : g1[0];
    unsigned short* rp = (att ? rpadI : rpadR) + (size_t)b * PADN * CD;
    __shared__ float t[64][65];
    const int tt = threadIdx.x;
    {
        const int c = tt >> 2, w0 = (tt & 3) * 16;
        const float* p = resid + ((size_t)b * CD + c) * NPOS + mt * 64 + w0;
#pragma unroll
        for (int j = 0; j < 16; j += 4) {
            float4 v = *(const float4*)(p + j);
            t[c][w0 + j] = v.x; t[c][w0 + j + 1] = v.y;
            t[c][w0 + j + 2] = v.z; t[c][w0 + j + 3] = v.w;
        }
    }
    __syncthreads();
    const int c = tt & 63, mq = tt >> 6;
    const size_t ob = (((size_t)att * NB + b) * NSEG) * NPOS * CD;
    const size_t mb = (((size_t)att * NB + b) * NSEG) * NPOS;
    for (int p = 0; p < 16; ++p) {
        const int mloc = mq * 16 + p;
        const int m = mt * 64 + mloc;
        float mm[NSEG], llv[NSEG];
#pragma unroll
        for (int s = 0; s < NSEG; ++s) {
            mm[s] = ml[(mb + (size_t)s * NPOS + m) * 2];
            llv[s] = ml[(mb + (size_t)s * NPOS + m) * 2 + 1];
        }
        float M = mm[0];
#pragma unroll
        for (int s = 1; s < NSEG; ++s) M = fmaxf(M, mm[s]);
        float Ov = 0.f, L = 0.f;
#pragma unroll
        for (int s = 0; s < NSEG; ++s) {
            const float wgt = __ocml_exp2_f32(mm[s] - M);
            L += wgt * llv[s];
            Ov += wgt * Opart[ob + ((size_t)s * NPOS + m) * CD + c];
        }
        const float val = fmaf(gamma, Ov / L, t[c][mloc]);
        const int h = m >> 6, w_ = m & 63;
        rp[((size_t)((h + 1) * PADW) + (w_ + 1)) * CD + c] = f2bf(val);
    }
}

// ---------------------------------------------------------------------------
extern "C" void kernel_launch(void* const* d_in, const int* in_sizes, int n_in,
                              void* d_out, int out_size, void* d_ws, size_t ws_size,
                              hipStream_t stream)
{
    const float* x    = (const float*)d_in[0];
    const float* y    = (const float*)d_in[1];
    const float* q_w  = (const float*)d_in[2];
    const float* q_s  = (const float*)d_in[3];
    const float* q_b  = (const float*)d_in[4];
    const float* rk_w = (const float*)d_in[5];
    const float* rk_s = (const float*)d_in[6];
    const float* rk_b = (const float*)d_in[7];
    const float* rv_w = (const float*)d_in[8];
    const float* rv_s = (const float*)d_in[9];
    const float* rv_b = (const float*)d_in[10];
    const float* ik_w = (const float*)d_in[11];
    const float* ik_s = (const float*)d_in[12];
    const float* ik_b = (const float*)d_in[13];
    const float* iv_w = (const float*)d_in[14];
    const float* iv_s = (const float*)d_in[15];
    const float* iv_b = (const float*)d_in[16];
    const float* sr_w = (const float*)d_in[17];
    const float* sr_s = (const float*)d_in[18];
    const float* sr_b = (const float*)d_in[19];
    const float* g1   = (const float*)d_in[20];
    const float* g2   = (const float*)d_in[21];

    char* ws = (char*)d_ws;
    size_t off = 0;
    auto alloc = [&](size_t bytes) {
        void* p = ws + off; off += (bytes + 255) & ~(size_t)255; return p;
    };
    const size_t PADB = (size_t)NB * PADN * CD * 2;
    unsigned short* xpad  = (unsigned short*)alloc(PADB);
    unsigned short* ypad  = (unsigned short*)alloc(PADB);
    unsigned short* rpadR = (unsigned short*)alloc(PADB);
    unsigned short* rpadI = (unsigned short*)alloc(PADB);
    unsigned short* Qt  = (unsigned short*)alloc((size_t)NB * NPOS * CD * 2);
    unsigned short* KtR = (unsigned short*)alloc((size_t)NB * NPOS * CD * 2);
    unsigned short* KtI = (unsigned short*)alloc((size_t)NB * NPOS * CD * 2);
    unsigned short* VR  = (unsigned short*)alloc((size_t)NB * NPOS * CD * 2);
    unsigned short* VI  = (unsigned short*)alloc((size_t)NB * NPOS * CD * 2);
    unsigned short* Wf  = (unsigned short*)alloc((size_t)144 * 4 * 64 * 16);
    float* Opart = (float*)alloc((size_t)2 * NB * NSEG * NPOS * CD * 4);
    float* mlb   = (float*)alloc((size_t)2 * NB * NSEG * NPOS * 2 * 4);

    // prep: halo-zero + weight repack + input pack (one launch, no memset)
    prep_kernel<<<dim3(672), 256, 0, stream>>>(
        x, y, q_w, rk_w, rv_w, ik_w, iv_w, sr_w,
        q_s, rk_s, rv_s, ik_s, iv_s, sr_s, xpad, Wf);
    // 5 pre-attention convs, co-split (10 z-slices)
    conv_mfma_kernel<<<dim3(64, NB, 10), 256, 0, stream>>>(
        xpad, ypad, rpadR, rpadI, Wf,
        q_b, rk_b, rv_b, ik_b, iv_b, sr_b,
        Qt, KtR, VR, KtI, VI, nullptr, 0);
    // FIX r4: grid must cover 64 mblk x 4 b x 2 att x 4 seg = 2048 blocks
    attn_kernel<<<dim3(64 * NB * 2 * NSEG), 256, 0, stream>>>(
        Qt, KtR, KtI, VR, VI, Opart, mlb);
    combine_kernel<<<dim3(64, NB, 2), 256, 0, stream>>>(
        Opart, mlb, x, y, g1, g2, rpadR, rpadI);
    // final SR conv -> d_out fp32 NCHW (co-split, 2 z-slices)
    conv_mfma_kernel<<<dim3(64, NB, 2), 256, 0, stream>>>(
        xpad, ypad, rpadR, rpadI, Wf,
        q_b, rk_b, rv_b, ik_b, iv_b, sr_b,
        Qt, KtR, VR, KtI, VI, (float*)d_out, 5);
}

// Round 6
// 220.237 us; speedup vs baseline: 1.4152x; 1.0585x over previous
//
#include <hip/hip_runtime.h>
#include <hip/hip_bf16.h>

#define NPOS 4096          // 64*64 positions
#define CD   64            // channels
#define NB   4             // batch
#define PADW 66
#define PADN (66*66)       // padded positions (zero halo)
#define NSEG 4             // attention n-split
#define NT   (NPOS / NSEG / 64)
#define LOG2E 1.4426950408889634f

extern "C" __device__ float __ocml_exp2_f32(float);

typedef __bf16 bf16x8_t __attribute__((ext_vector_type(8)));
typedef float  f32x4_t  __attribute__((ext_vector_type(4)));

static __device__ __forceinline__ unsigned short f2bf(float f) {
    return __builtin_bit_cast(unsigned short, __float2bfloat16(f));
}

static __device__ __forceinline__ void gload_lds16(const void* g, void* l) {
    __builtin_amdgcn_global_load_lds(
        (const __attribute__((address_space(1))) void*)g,
        (__attribute__((address_space(3))) void*)l, 16, 0, 0);
}

static __device__ __forceinline__ unsigned cvtpk_bf16(float lo, float hi) {
    unsigned r;
    asm("v_cvt_pk_bf16_f32 %0, %1, %2" : "=v"(r) : "v"(lo), "v"(hi));
    return r;
}

// ---------------------------------------------------------------------------
// prep: fused {halo-zero, weight-repack, input-pack} in one launch.
// grid 672 = 16 halo + 144 wrepack + 512 pack. block 256.
// ---------------------------------------------------------------------------
__global__ __launch_bounds__(256) void prep_kernel(
    const float* __restrict__ x, const float* __restrict__ y,
    const float* __restrict__ qw, const float* __restrict__ rkw,
    const float* __restrict__ rvw, const float* __restrict__ ikw,
    const float* __restrict__ ivw, const float* __restrict__ srw,
    const float* __restrict__ qs, const float* __restrict__ rks,
    const float* __restrict__ rvs, const float* __restrict__ iks,
    const float* __restrict__ ivs, const float* __restrict__ srs,
    unsigned short* __restrict__ pads, unsigned short* __restrict__ Wf)
{
    const int bx = blockIdx.x;
    if (bx < 16) {
        unsigned short* p = pads + (size_t)bx * PADN * CD;
        const uint4 z = make_uint4(0, 0, 0, 0);
        for (int idx = threadIdx.x; idx < 260 * 8; idx += 256) {
            const int pi = idx >> 3, chn = idx & 7;
            int pos;
            if (pi < 66)       pos = pi;
            else if (pi < 132) pos = 65 * PADW + (pi - 66);
            else { const int rem = pi - 132;
                   pos = (1 + (rem >> 1)) * PADW + ((rem & 1) ? 65 : 0); }
            *(uint4*)(p + (size_t)pos * CD + chn * 8) = z;
        }
        return;
    }
    if (bx < 160) {
        const int f = bx - 16;
        const float* w; const float* s; int cin, local;
        if (f < 36)       { w = qw;  s = qs;  cin = 128; local = f; }
        else if (f < 54)  { w = rkw; s = rks; cin = 64;  local = f - 36; }
        else if (f < 72)  { w = rvw; s = rvs; cin = 64;  local = f - 54; }
        else if (f < 90)  { w = ikw; s = iks; cin = 64;  local = f - 72; }
        else if (f < 108) { w = ivw; s = ivs; cin = 64;  local = f - 90; }
        else              { w = srw; s = srs; cin = 128; local = f - 108; }
        const int src = (cin == 128) ? local / 18 : 0;
        const int rem = (cin == 128) ? local % 18 : local;
        const int tap = rem >> 1, kt = rem & 1;
        const int t = threadIdx.x, cot = t >> 6, l = t & 63;
        const int co = cot * 16 + (l & 15);
        const float kmul = ((f >= 36 && f < 54) || (f >= 72 && f < 90)) ? LOG2E : 1.0f;
        const float sc = s[co] * kmul;
        unsigned short us[8];
#pragma unroll
        for (int e = 0; e < 8; ++e) {
            const int ci = src * 64 + kt * 32 + ((l >> 4) * 8) + e;
            us[e] = f2bf(w[((size_t)co * cin + ci) * 9 + tap] * sc);
        }
        *(uint4*)(Wf + ((size_t)(f * 4 + cot) * 64 + l) * 8) = *(uint4*)us;
        return;
    }
    {
        const int idx = bx - 160;
        const int h = idx & 63, b = (idx >> 6) & 3, src = idx >> 8;
        const float* in = src ? y : x;
        unsigned short* out = pads + (size_t)src * NB * PADN * CD;
        __shared__ float t[64][65];
        const int tt = threadIdx.x;
        {
            const int ci = tt >> 2, w0 = (tt & 3) * 16;
            const float* p = in + ((size_t)b * 64 + ci) * NPOS + h * 64 + w0;
#pragma unroll
            for (int j = 0; j < 16; j += 4) {
                float4 v = *(const float4*)(p + j);
                t[ci][w0 + j] = v.x; t[ci][w0 + j + 1] = v.y;
                t[ci][w0 + j + 2] = v.z; t[ci][w0 + j + 3] = v.w;
            }
        }
        __syncthreads();
        const int w = tt >> 2, c0 = (tt & 3) * 16;
        unsigned short us[16];
#pragma unroll
        for (int j = 0; j < 16; ++j) us[j] = f2bf(t[c0 + j][w]);
        unsigned short* q = out + ((size_t)b * PADN + (h + 1) * PADW + (w + 1)) * CD + c0;
        *(uint4*)q = *(uint4*)us;
        *(uint4*)(q + 8) = *(uint4*)(us + 8);
    }
}

// ---------------------------------------------------------------------------
// Implicit-GEMM conv3x3 via MFMA, weight frags staged in LDS per (src,ky)
// chunk (12 slots x 1KB). Block = TWO h rows x 64 pos x 32 co; 4 waves,
// wave wv: row = wv>>1, pos-half = (wv&1)*32. Each 12KB stage now feeds
// 24 MFMAs/wave (2x r5). grid (32 rowpair, NB, 2*nconv): z>>1=conv, z&1=co half.
// layouts: 0 = bf16 [n][co], 1 = bf16 [co][n], 2 = fp32 [co][n] (d_out)
// K-producing convs (1,3) get bias x log2(e) (weights already scaled).
// ---------------------------------------------------------------------------
__global__ __launch_bounds__(256) void conv_mfma_kernel(
    const unsigned short* __restrict__ xpad, const unsigned short* __restrict__ ypad,
    const unsigned short* __restrict__ rpadR, const unsigned short* __restrict__ rpadI,
    const unsigned short* __restrict__ Wf,
    const float* __restrict__ qb, const float* __restrict__ rkb,
    const float* __restrict__ rvb, const float* __restrict__ ikb,
    const float* __restrict__ ivb, const float* __restrict__ srb,
    unsigned short* __restrict__ Qt, unsigned short* __restrict__ KtR,
    unsigned short* __restrict__ VR, unsigned short* __restrict__ KtI,
    unsigned short* __restrict__ VI, float* __restrict__ outf,
    int convid_base)
{
    const int conv = convid_base + (blockIdx.z >> 1);
    const int ch   = blockIdx.z & 1;            // co half
    const int rp = blockIdx.x, b = blockIdx.y;
    const unsigned short *in0, *in1; const float* bias;
    int nsrc, wfbase, layout; void* outp;
    switch (conv) {
        case 0:  in0 = xpad;  in1 = ypad;  nsrc = 2; wfbase = 0;   bias = qb;  outp = Qt;  layout = 0; break;
        case 1:  in0 = xpad;  in1 = 0;     nsrc = 1; wfbase = 36;  bias = rkb; outp = KtR; layout = 0; break;
        case 2:  in0 = xpad;  in1 = 0;     nsrc = 1; wfbase = 54;  bias = rvb; outp = VR;  layout = 1; break;
        case 3:  in0 = ypad;  in1 = 0;     nsrc = 1; wfbase = 72;  bias = ikb; outp = KtI; layout = 0; break;
        case 4:  in0 = ypad;  in1 = 0;     nsrc = 1; wfbase = 90;  bias = ivb; outp = VI;  layout = 1; break;
        default: in0 = rpadR; in1 = rpadI; nsrc = 2; wfbase = 108; bias = srb; outp = outf; layout = 2; break;
    }
    const float bmul = (conv == 1 || conv == 3) ? LOG2E : 1.0f;
    const int lane = threadIdx.x & 63, wv = threadIdx.x >> 6;
    const int l15 = lane & 15, g = lane >> 4;
    const int hrow = rp * 2 + (wv >> 1);        // this wave's h row
    const int posg = (wv & 1) * 32;             // pos half within the row

    __shared__ unsigned short Wl[12 * 512];     // 12 slots x 1KB

    f32x4_t acc[2][2];                          // [pf][cc]
#pragma unroll
    for (int i = 0; i < 2; ++i)
#pragma unroll
        for (int j = 0; j < 2; ++j) acc[i][j] = (f32x4_t){0.f, 0.f, 0.f, 0.f};

    const int nchunk = nsrc * 3;
    for (int c = 0; c < nchunk; ++c) {
        const int src = (c >= 3) ? 1 : 0;
        const int ky  = c - src * 3;
        if (c) __syncthreads();
#pragma unroll
        for (int j = 0; j < 3; ++j) {
            const int slot = wv * 3 + j;
            const int fj = slot >> 1, cotl = slot & 1;
            const int fg = wfbase + c * 6 + fj;
            gload_lds16(Wf + ((size_t)(fg * 4 + ch * 2 + cotl) * 64 + lane) * 8,
                        Wl + slot * 512);
        }
        __syncthreads();
        const unsigned short* base = (src ? in1 : in0) + (size_t)b * PADN * CD;
#pragma unroll
        for (int pf = 0; pf < 2; ++pf) {
#pragma unroll
            for (int kx = 0; kx < 3; ++kx) {
                const int pos = (hrow + ky) * PADW + posg + pf * 16 + kx + l15;
                const unsigned short* ap = base + (size_t)pos * CD + g * 8;
#pragma unroll
                for (int kt = 0; kt < 2; ++kt) {
                    bf16x8_t a = *(const bf16x8_t*)(ap + kt * 32);
                    const int fj = kx * 2 + kt;
#pragma unroll
                    for (int cc = 0; cc < 2; ++cc) {
                        bf16x8_t bfr = *(const bf16x8_t*)(Wl + (size_t)(fj * 2 + cc) * 512 + lane * 8);
                        acc[pf][cc] = __builtin_amdgcn_mfma_f32_16x16x32_bf16(a, bfr, acc[pf][cc], 0, 0, 0);
                    }
                }
            }
        }
    }

#pragma unroll
    for (int pf = 0; pf < 2; ++pf) {
        const int nb4 = hrow * 64 + posg + pf * 16 + g * 4;
        if (layout == 0) {
            unsigned short* o = (unsigned short*)outp + (size_t)b * NPOS * CD;
#pragma unroll
            for (int cc = 0; cc < 2; ++cc) {
                const int co = (ch * 2 + cc) * 16 + l15;
                const float bv = bias[co] * bmul;
#pragma unroll
                for (int r = 0; r < 4; ++r)
                    o[(size_t)(nb4 + r) * CD + co] = f2bf(fmaxf(acc[pf][cc][r] + bv, 0.f));
            }
        } else if (layout == 1) {
            unsigned short* o = (unsigned short*)outp + (size_t)b * CD * NPOS;
#pragma unroll
            for (int cc = 0; cc < 2; ++cc) {
                const int cch = (ch * 2 + cc) * 16 + l15;
                const float bv = bias[cch];
                unsigned short us[4];
#pragma unroll
                for (int r = 0; r < 4; ++r) us[r] = f2bf(fmaxf(acc[pf][cc][r] + bv, 0.f));
                *(uint2*)(o + (size_t)cch * NPOS + nb4) = *(uint2*)us;
            }
        } else {
            float* o = (float*)outp + (size_t)b * CD * NPOS;
#pragma unroll
            for (int cc = 0; cc < 2; ++cc) {
                const int cch = (ch * 2 + cc) * 16 + l15;
                const float bv = bias[cch];
                f32x4_t v;
#pragma unroll
                for (int r = 0; r < 4; ++r) v[r] = fmaxf(acc[pf][cc][r] + bv, 0.f);
                *(f32x4_t*)(o + (size_t)cch * NPOS + nb4) = v;
            }
        }
    }
}

// ---------------------------------------------------------------------------
// Flash attention over an n-segment (base-2 softmax, defer-max, VALU-lean).
//   Qt/Kt bf16 [b][n][64]; V bf16 [b][c][n]. K pre-scaled by log2(e).
// 2048 blocks: fid&1=att, (fid>>1)&3=b (fid&7 = XCD group), (fid>>3)&3=seg,
// mblk=fid>>5. block 256 = 4 waves x 16 m rows.
// Q+V double-buffered in LDS via global_load_lds (XOR chunk swizzle on the
// GLOBAL source; linear LDS dest; same XOR on reads). ONE __syncthreads/iter;
// stage(next) issued right after it. cvt_pk_bf16 packing, exp2f, max3 chains.
// Opart fp32 [att][b][seg][m][c]; ml fp32 [att][b][seg][m][2] (base-2 m, l).
// ---------------------------------------------------------------------------
__global__ __launch_bounds__(256) void attn_kernel(
    const unsigned short* __restrict__ Qt,
    const unsigned short* __restrict__ KtR, const unsigned short* __restrict__ KtI,
    const unsigned short* __restrict__ VR,  const unsigned short* __restrict__ VI,
    float* __restrict__ Opart, float* __restrict__ ml)
{
    const int fid = blockIdx.x;
    const int att = fid & 1;
    const int b   = (fid >> 1) & 3;
    const int seg = (fid >> 3) & 3;
    const int mblk = fid >> 5;
    const int lane = threadIdx.x & 63, wv = threadIdx.x >> 6;
    const int l15 = lane & 15, g = lane >> 4;
    const int m0 = mblk * 64 + wv * 16;

    const unsigned short* Qb = Qt + (size_t)b * NPOS * CD;
    const unsigned short* Kb = (att ? KtI : KtR) + (size_t)b * NPOS * CD;
    const unsigned short* Vb = (att ? VI : VR) + (size_t)b * CD * NPOS;

    __shared__ unsigned short Qs[2][64 * 64];
    __shared__ unsigned short Vs[2][64 * 64];
    __shared__ unsigned short plds[4][16 * 68];
    unsigned short* pl = plds[wv];

    const bf16x8_t bK0 = *(const bf16x8_t*)&Kb[(size_t)(m0 + l15) * CD + g * 8];
    const bf16x8_t bK1 = *(const bf16x8_t*)&Kb[(size_t)(m0 + l15) * CD + 32 + g * 8];

    f32x4_t O[4];
#pragma unroll
    for (int i = 0; i < 4; ++i) O[i] = (f32x4_t){0.f, 0.f, 0.f, 0.f};
    float mrun = -3.0e38f, lsum = 0.f;   // per-lane partials

    const int csw = (lane & 7) ^ ((lane >> 3) & 7);   // swizzled source chunk
    const int sx = l15 & 7;                            // read-side XOR key
    const int nbase = seg * (NPOS / NSEG);

    // hoisted per-thread staging pointers (advance by constants per tile)
    const int rq = wv * 16 + (lane >> 3);
    const unsigned short* qsrc0 = Qb + (size_t)(nbase + rq) * CD + csw * 8;
    const unsigned short* qsrc1 = qsrc0 + (size_t)8 * CD;
    const unsigned short* vsrc0 = Vb + (size_t)rq * NPOS + nbase + csw * 8;
    const unsigned short* vsrc1 = vsrc0 + (size_t)8 * NPOS;
    unsigned short* qdst = &Qs[0][(wv * 16) * 64];     // wave-uniform dest
    unsigned short* vdst = &Vs[0][(wv * 16) * 64];

#define STAGE(buf, itv) do {                                                  \
        const size_t qo = (size_t)(itv) * (64 * CD);                          \
        const size_t vo = (size_t)(itv) * 64;                                 \
        gload_lds16(qsrc0 + qo, qdst + (buf) * 4096);                         \
        gload_lds16(qsrc1 + qo, qdst + (buf) * 4096 + 512);                   \
        gload_lds16(vsrc0 + vo, vdst + (buf) * 4096);                         \
        gload_lds16(vsrc1 + vo, vdst + (buf) * 4096 + 512);                   \
    } while (0)

    STAGE(0, 0);

    for (int it = 0; it < NT; ++it) {
        const int cur = it & 1;
        __syncthreads();   // drains stage(cur) DMAs; prev-iter reads done
        if (it + 1 < NT) STAGE(cur ^ 1, it + 1);   // overlaps compute below

        // ---- QK^T: St[row=n_local, col=m] ----
        f32x4_t St[4];
        __builtin_amdgcn_s_setprio(1);
#pragma unroll
        for (int nt = 0; nt < 4; ++nt) {
            const unsigned short* qr = &Qs[cur][(nt * 16 + l15) * 64];
            bf16x8_t a0 = *(const bf16x8_t*)(qr + (g ^ sx) * 8);
            bf16x8_t a1 = *(const bf16x8_t*)(qr + ((4 + g) ^ sx) * 8);
            f32x4_t c = (f32x4_t){0.f, 0.f, 0.f, 0.f};
            c = __builtin_amdgcn_mfma_f32_16x16x32_bf16(a0, bK0, c, 0, 0, 0);
            c = __builtin_amdgcn_mfma_f32_16x16x32_bf16(a1, bK1, c, 0, 0, 0);
            St[nt] = c;
        }
        __builtin_amdgcn_s_setprio(0);

        // ---- online softmax, base-2, defer-max; max3-shaped chains ----
        float tmax = St[0][0];
#pragma unroll
        for (int nt = 0; nt < 4; ++nt) {
            tmax = fmaxf(fmaxf(tmax, St[nt][0]), St[nt][1]);   // -> v_max3
            tmax = fmaxf(fmaxf(tmax, St[nt][2]), St[nt][3]);
        }
        if (!__all(tmax <= mrun + 12.0f)) {
            float tr = fmaxf(tmax, __shfl_xor(tmax, 16));
            tr = fmaxf(tr, __shfl_xor(tr, 32));
            const float mnew = fmaxf(mrun, tr);
            const float corr = __builtin_amdgcn_exp2f(mrun - mnew);
            lsum *= corr;
#pragma unroll
            for (int i = 0; i < 4; ++i) {
                O[i][0] *= corr; O[i][1] *= corr; O[i][2] *= corr; O[i][3] *= corr;
            }
            mrun = mnew;
        }
        unsigned int pw[8];
#pragma unroll
        for (int nt = 0; nt < 4; ++nt) {
            float p0 = __builtin_amdgcn_exp2f(St[nt][0] - mrun);
            float p1 = __builtin_amdgcn_exp2f(St[nt][1] - mrun);
            float p2 = __builtin_amdgcn_exp2f(St[nt][2] - mrun);
            float p3 = __builtin_amdgcn_exp2f(St[nt][3] - mrun);
            lsum += (p0 + p1) + (p2 + p3);
            pw[nt * 2 + 0] = cvtpk_bf16(p0, p1);
            pw[nt * 2 + 1] = cvtpk_bf16(p2, p3);
        }
        // ---- P -> per-wave LDS ----
#pragma unroll
        for (int nt = 0; nt < 4; ++nt)
            *(uint2*)&pl[l15 * 68 + nt * 16 + g * 4] =
                make_uint2(pw[nt * 2], pw[nt * 2 + 1]);

        // ---- PV: O[c,m] += V[c,:] P[m,:] ----
        __builtin_amdgcn_s_setprio(1);
#pragma unroll
        for (int nc = 0; nc < 2; ++nc) {
            union { bf16x8_t v; uint2 d2[2]; } bp;
            bp.d2[0] = *(uint2*)&pl[l15 * 68 + nc * 32 + g * 8];
            bp.d2[1] = *(uint2*)&pl[l15 * 68 + nc * 32 + g * 8 + 4];
#pragma unroll
            for (int ct = 0; ct < 4; ++ct) {
                bf16x8_t av = *(const bf16x8_t*)
                    (&Vs[cur][(ct * 16 + l15) * 64 + (((nc * 4 + g) ^ sx) * 8)]);
                O[ct] = __builtin_amdgcn_mfma_f32_16x16x32_bf16(av, bp.v, O[ct], 0, 0, 0);
            }
        }
        __builtin_amdgcn_s_setprio(0);
    }

    // ---- epilogue: reduce lsum across g, write partials ----
    float lred = lsum + __shfl_xor(lsum, 16);
    lred += __shfl_xor(lred, 32);
    float* Ob = Opart + ((((size_t)att * NB + b) * NSEG + seg) * NPOS) * CD;
    const int m = m0 + l15;
#pragma unroll
    for (int ct = 0; ct < 4; ++ct)
        *(f32x4_t*)(Ob + (size_t)m * CD + ct * 16 + g * 4) = O[ct];
    if (g == 0) {
        float* mlb = ml + ((((size_t)att * NB + b) * NSEG + seg) * NPOS + m) * 2;
        mlb[0] = mrun; mlb[1] = lred;
    }
#undef STAGE
}

// ---------------------------------------------------------------------------
// Combine NSEG partials -> refine = gamma*O/L + resid, bf16 into padded
// layout for the SR conv. grid (256 mtile16, NB, 2 att). Base-2 weights.
// ---------------------------------------------------------------------------
__global__ __launch_bounds__(256) void combine_kernel(
    const float* __restrict__ Opart, const float* __restrict__ ml,
    const float* __restrict__ x, const float* __restrict__ y,
    const float* __restrict__ g1, const float* __restrict__ g2,
    unsigned short* __restrict__ rpadR, unsigned short* __restrict__ rpadI)
{
    const int mt = blockIdx.x, b = blockIdx.y, att = blockIdx.z;
    const float* resid = att ? x : y;
    const float gamma = att ? g2[0] : g1[0];
    unsigned short* rp = (att ? rpadI : rpadR) + (size_t)b * PADN * CD;
    __shared__ float t[64][17];
    const int tt = threadIdx.x;
    {
        const int c = tt >> 2, m4 = (tt & 3) * 4;
        const float4 v = *(const float4*)(resid + ((size_t)b * CD + c) * NPOS + mt * 16 + m4);
        t[c][m4] = v.x; t[c][m4 + 1] = v.y; t[c][m4 + 2] = v.z; t[c][m4 + 3] = v.w;
    }
    __syncthreads();
    const int c = tt & 63, mq = tt >> 6;
    const size_t ob = (((size_t)att * NB + b) * NSEG) * NPOS * CD;
    const size_t mb = (((size_t)att * NB + b) * NSEG) * NPOS;
#pragma unroll
    for (int p = 0; p < 4; ++p) {
        const int mloc = mq * 4 + p;
        const int m = mt * 16 + mloc;
        float mm[NSEG], llv[NSEG];
#pragma unroll
        for (int s = 0; s < NSEG; ++s) {
            mm[s] = ml[(mb + (size_t)s * NPOS + m) * 2];
            llv[s] = ml[(mb + (size_t)s * NPOS + m) * 2 + 1];
        }
        float M = mm[0];
#pragma unroll
        for (int s = 1; s < NSEG; ++s) M = fmaxf(M, mm[s]);
        float Ov = 0.f, L = 0.f;
#pragma unroll
        for (int s = 0; s < NSEG; ++s) {
            const float wgt = __ocml_exp2_f32(mm[s] - M);
            L += wgt * llv[s];
            Ov += wgt * Opart[ob + ((size_t)s * NPOS + m) * CD + c];
        }
        const float val = fmaf(gamma, Ov / L, t[c][mloc]);
        const int h = m >> 6, w_ = m & 63;
        rp[((size_t)((h + 1) * PADW) + (w_ + 1)) * CD + c] = f2bf(val);
    }
}

// ---------------------------------------------------------------------------
extern "C" void kernel_launch(void* const* d_in, const int* in_sizes, int n_in,
                              void* d_out, int out_size, void* d_ws, size_t ws_size,
                              hipStream_t stream)
{
    const float* x    = (const float*)d_in[0];
    const float* y    = (const float*)d_in[1];
    const float* q_w  = (const float*)d_in[2];
    const float* q_s  = (const float*)d_in[3];
    const float* q_b  = (const float*)d_in[4];
    const float* rk_w = (const float*)d_in[5];
    const float* rk_s = (const float*)d_in[6];
    const float* rk_b = (const float*)d_in[7];
    const float* rv_w = (const float*)d_in[8];
    const float* rv_s = (const float*)d_in[9];
    const float* rv_b = (const float*)d_in[10];
    const float* ik_w = (const float*)d_in[11];
    const float* ik_s = (const float*)d_in[12];
    const float* ik_b = (const float*)d_in[13];
    const float* iv_w = (const float*)d_in[14];
    const float* iv_s = (const float*)d_in[15];
    const float* iv_b = (const float*)d_in[16];
    const float* sr_w = (const float*)d_in[17];
    const float* sr_s = (const float*)d_in[18];
    const float* sr_b = (const float*)d_in[19];
    const float* g1   = (const float*)d_in[20];
    const float* g2   = (const float*)d_in[21];

    char* ws = (char*)d_ws;
    size_t off = 0;
    auto alloc = [&](size_t bytes) {
        void* p = ws + off; off += (bytes + 255) & ~(size_t)255; return p;
    };
    const size_t PADB = (size_t)NB * PADN * CD * 2;
    unsigned short* xpad  = (unsigned short*)alloc(PADB);
    unsigned short* ypad  = (unsigned short*)alloc(PADB);
    unsigned short* rpadR = (unsigned short*)alloc(PADB);
    unsigned short* rpadI = (unsigned short*)alloc(PADB);
    unsigned short* Qt  = (unsigned short*)alloc((size_t)NB * NPOS * CD * 2);
    unsigned short* KtR = (unsigned short*)alloc((size_t)NB * NPOS * CD * 2);
    unsigned short* KtI = (unsigned short*)alloc((size_t)NB * NPOS * CD * 2);
    unsigned short* VR  = (unsigned short*)alloc((size_t)NB * NPOS * CD * 2);
    unsigned short* VI  = (unsigned short*)alloc((size_t)NB * NPOS * CD * 2);
    unsigned short* Wf  = (unsigned short*)alloc((size_t)144 * 4 * 64 * 16);
    float* Opart = (float*)alloc((size_t)2 * NB * NSEG * NPOS * CD * 4);
    float* mlb   = (float*)alloc((size_t)2 * NB * NSEG * NPOS * 2 * 4);

    // prep: halo-zero + weight repack + input pack (one launch, no memset)
    prep_kernel<<<dim3(672), 256, 0, stream>>>(
        x, y, q_w, rk_w, rv_w, ik_w, iv_w, sr_w,
        q_s, rk_s, rv_s, ik_s, iv_s, sr_s, xpad, Wf);
    // 5 pre-attention convs, 2-row blocks, co-split (10 z-slices)
    conv_mfma_kernel<<<dim3(32, NB, 10), 256, 0, stream>>>(
        xpad, ypad, rpadR, rpadI, Wf,
        q_b, rk_b, rv_b, ik_b, iv_b, sr_b,
        Qt, KtR, VR, KtI, VI, nullptr, 0);
    // 64 mblk x 4 b x 2 att x 4 seg = 2048 blocks
    attn_kernel<<<dim3(64 * NB * 2 * NSEG), 256, 0, stream>>>(
        Qt, KtR, KtI, VR, VI, Opart, mlb);
    combine_kernel<<<dim3(256, NB, 2), 256, 0, stream>>>(
        Opart, mlb, x, y, g1, g2, rpadR, rpadI);
    // final SR conv -> d_out fp32 NCHW (2-row blocks, co-split)
    conv_mfma_kernel<<<dim3(32, NB, 2), 256, 0, stream>>>(
        xpad, ypad, rpadR, rpadI, Wf,
        q_b, rk_b, rv_b, ik_b, iv_b, sr_b,
        Qt, KtR, VR, KtI, VI, (float*)d_out, 5);
}